// Round 1
// baseline (145.526 us; speedup 1.0000x reference)
//
#include <hip/hip_runtime.h>
#include <math.h>

#define B   64
#define DQ  512
#define DO  256
#define NH  8
#define DH  32
#define HW  1024

// ---------------------------------------------------------------- K1: qv = q @ w_q.T + b_q
__global__ void k1_qv(const float* __restrict__ q, const float* __restrict__ w_q,
                      const float* __restrict__ b_q, float* __restrict__ qv) {
    __shared__ float qs[DQ];
    int b = blockIdx.x, t = threadIdx.x;
    qs[t]       = q[b*DQ + t];
    qs[t + 256] = q[b*DQ + t + 256];
    __syncthreads();
    float acc = b_q[t];
    const float4* w4 = reinterpret_cast<const float4*>(w_q + t*DQ);
    #pragma unroll 4
    for (int k4 = 0; k4 < DQ/4; ++k4) {
        float4 w = w4[k4];
        acc += qs[k4*4+0]*w.x + qs[k4*4+1]*w.y + qs[k4*4+2]*w.z + qs[k4*4+3]*w.w;
    }
    qv[b*DO + t] = acc;
}

// ---------------------------------------------------------------- K2: fold qv into kc/kd weights
__global__ void k2_wqk(const float* __restrict__ qv,
                       const float* __restrict__ w_kc, const float* __restrict__ b_kc,
                       const float* __restrict__ w_kd, const float* __restrict__ b_kd,
                       const float* __restrict__ temp_c, const float* __restrict__ temp_d,
                       float* __restrict__ wqkc, float* __restrict__ wqkd,
                       float* __restrict__ qbc, float* __restrict__ qbd) {
    int bn = blockIdx.x;              // b*8 + n
    int n  = bn & 7;
    int t  = threadIdx.x;             // c
    __shared__ float qvs[DH];
    if (t < DH) qvs[t] = qv[(bn >> 3)*DO + n*DH + t];
    __syncthreads();
    float itc = 1.0f / temp_c[0];
    float itd = 1.0f / temp_d[0];
    float ac = 0.f, ad = 0.f;
    #pragma unroll
    for (int d = 0; d < DH; ++d) {
        float qd = qvs[d];
        ac += qd * w_kc[(n*DH + d)*DO + t];
        ad += qd * w_kd[(n*DH + d)*DO + t];
    }
    wqkc[bn*DO + t] = ac * itc;
    wqkd[bn*DO + t] = ad * itd;
    if (t == 0) {
        float sc = 0.f, sd = 0.f;
        for (int d = 0; d < DH; ++d) { sc += qvs[d]*b_kc[n*DH + d]; sd += qvs[d]*b_kd[n*DH + d]; }
        qbc[bn] = sc * itc;
        qbd[bn] = sd * itd;
    }
}

// ---------------------------------------------------------------- K3: logits (collect) + sigmoid gate (diffuse)
__global__ void k3_logits(const float* __restrict__ v,
                          const float* __restrict__ wqkc, const float* __restrict__ wqkd,
                          const float* __restrict__ qbc, const float* __restrict__ qbd,
                          float* __restrict__ lc, float* __restrict__ gate) {
    int b = blockIdx.y;
    int s = blockIdx.x*256 + threadIdx.x;
    float ac[NH] = {0.f,0.f,0.f,0.f,0.f,0.f,0.f,0.f};
    float ad[NH] = {0.f,0.f,0.f,0.f,0.f,0.f,0.f,0.f};
    const float* vb = v    + (size_t)b*DO*HW;
    const float* wc = wqkc + b*NH*DO;
    const float* wd = wqkd + b*NH*DO;
    for (int c = 0; c < DO; ++c) {
        float vv = vb[c*HW + s];
        #pragma unroll
        for (int n = 0; n < NH; ++n) {
            ac[n] += vv * wc[n*DO + c];
            ad[n] += vv * wd[n*DO + c];
        }
    }
    #pragma unroll
    for (int n = 0; n < NH; ++n) {
        int bn = b*NH + n;
        lc[bn*HW + s] = ac[n] + qbc[bn];
        float x = ad[n] + qbd[bn];
        gate[bn*HW + s] = 1.0f / (1.0f + __expf(-x));
    }
}

// ---------------------------------------------------------------- K4a: softmax over s per (b,n)
__global__ void k4a_softmax(const float* __restrict__ lc, float* __restrict__ p) {
    int bn = blockIdx.x, t = threadIdx.x;
    const float4* L = reinterpret_cast<const float4*>(lc + bn*HW);
    float4 x = L[t];
    __shared__ float red[256];
    float m = fmaxf(fmaxf(x.x, x.y), fmaxf(x.z, x.w));
    red[t] = m; __syncthreads();
    for (int o = 128; o > 0; o >>= 1) { if (t < o) red[t] = fmaxf(red[t], red[t+o]); __syncthreads(); }
    m = red[0]; __syncthreads();
    float e0 = __expf(x.x - m), e1 = __expf(x.y - m), e2 = __expf(x.z - m), e3 = __expf(x.w - m);
    red[t] = e0 + e1 + e2 + e3; __syncthreads();
    for (int o = 128; o > 0; o >>= 1) { if (t < o) red[t] += red[t+o]; __syncthreads(); }
    float inv = 1.0f / red[0];
    reinterpret_cast<float4*>(p + bn*HW)[t] = make_float4(e0*inv, e1*inv, e2*inv, e3*inv);
}

// ---------------------------------------------------------------- K4b: pooled vector pv[b,n,c] = sum_s p[s] v[c,s]
__global__ void k4b_pool(const float* __restrict__ v, const float* __restrict__ p,
                         float* __restrict__ pv) {
    int b  = blockIdx.y;
    int c0 = blockIdx.x * 64;
    int t  = threadIdx.x;
    int cl = t & 63, q = t >> 6;          // q: s-quarter, wave-uniform
    int c  = c0 + cl;
    const float4* v4 = reinterpret_cast<const float4*>(v + ((size_t)(b*DO + c))*HW + q*256);
    float acc[NH] = {0.f,0.f,0.f,0.f,0.f,0.f,0.f,0.f};
    for (int s4 = 0; s4 < 64; ++s4) {
        float4 vv = v4[s4];
        #pragma unroll
        for (int n = 0; n < NH; ++n) {
            float4 pp = reinterpret_cast<const float4*>(p + (b*NH + n)*HW + q*256)[s4];
            acc[n] += vv.x*pp.x + vv.y*pp.y + vv.z*pp.z + vv.w*pp.w;
        }
    }
    __shared__ float red[4][NH][64];
    #pragma unroll
    for (int n = 0; n < NH; ++n) red[q][n][cl] = acc[n];
    __syncthreads();
    if (t < 64) {
        #pragma unroll
        for (int n = 0; n < NH; ++n) {
            float sum = red[0][n][t] + red[1][n][t] + red[2][n][t] + red[3][n][t];
            pv[(b*NH + n)*DO + c0 + t] = sum;
        }
    }
}

// ---------------------------------------------------------------- K4c: attn[b,n,d] = w_v[nd,:]·pv + b_v[nd]
__global__ void k4c_attn(const float* __restrict__ pv, const float* __restrict__ w_v,
                         const float* __restrict__ b_v, float* __restrict__ attn) {
    int b = blockIdx.x, t = threadIdx.x;   // t = n*32 + d
    int n = t >> 5;
    __shared__ float pvs[NH*DO];
    for (int i = t; i < NH*DO; i += 256) pvs[i] = pv[b*NH*DO + i];
    __syncthreads();
    float acc = b_v[t];
    const float4* w4 = reinterpret_cast<const float4*>(w_v + t*DO);
    #pragma unroll 4
    for (int c4 = 0; c4 < DO/4; ++c4) {
        float4 w = w4[c4];
        int c = c4*4;
        acc += pvs[n*DO + c]*w.x + pvs[n*DO + c + 1]*w.y + pvs[n*DO + c + 2]*w.z + pvs[n*DO + c + 3]*w.w;
    }
    attn[b*NH*DH + t] = acc;
}

// ---------------------------------------------------------------- K5: out = leaky(bn(gate[s^T]*attn + v))
__global__ void k5_out(const float* __restrict__ v, const float* __restrict__ gate,
                       const float* __restrict__ attn,
                       const float* __restrict__ bn_g, const float* __restrict__ bn_b,
                       const float* __restrict__ bn_m, const float* __restrict__ bn_v,
                       float* __restrict__ out) {
    int c = blockIdx.x, b = blockIdx.y;
    int n = c >> 5, d = c & 31;
    int t = threadIdx.x;
    __shared__ float g[32*33];             // g[s>>5][s&31], stride 33 kills bank conflicts
    float4 gv = reinterpret_cast<const float4*>(gate + (b*NH + n)*HW)[t];
    int s0 = t*4;
    int ga = s0 >> 5, gb = s0 & 31;
    g[ga*33 + gb + 0] = gv.x;
    g[ga*33 + gb + 1] = gv.y;
    g[ga*33 + gb + 2] = gv.z;
    g[ga*33 + gb + 3] = gv.w;
    __syncthreads();
    float av   = attn[(b*NH + n)*DH + d];
    float inv  = bn_g[c] / sqrtf(bn_v[c] + 1e-5f);
    float mean = bn_m[c], beta = bn_b[c];
    size_t base = ((size_t)(b*DO + c))*HW;
    float4 r4 = reinterpret_cast<const float4*>(v + base)[t];
    int l = 4*t;
    int i_ = l >> 5, j_ = l & 31;          // output spatial (i_, j_..j_+3); gate index s = j*32 + i
    float x0 = g[(j_+0)*33 + i_]*av + r4.x;
    float x1 = g[(j_+1)*33 + i_]*av + r4.y;
    float x2 = g[(j_+2)*33 + i_]*av + r4.z;
    float x3 = g[(j_+3)*33 + i_]*av + r4.w;
    float y0 = (x0 - mean)*inv + beta; y0 = y0 >= 0.f ? y0 : 0.1f*y0;
    float y1 = (x1 - mean)*inv + beta; y1 = y1 >= 0.f ? y1 : 0.1f*y1;
    float y2 = (x2 - mean)*inv + beta; y2 = y2 >= 0.f ? y2 : 0.1f*y2;
    float y3 = (x3 - mean)*inv + beta; y3 = y3 >= 0.f ? y3 : 0.1f*y3;
    reinterpret_cast<float4*>(out + base)[t] = make_float4(y0, y1, y2, y3);
}

// ----------------------------------------------------------------
extern "C" void kernel_launch(void* const* d_in, const int* in_sizes, int n_in,
                              void* d_out, int out_size, void* d_ws, size_t ws_size,
                              hipStream_t stream) {
    const float* q      = (const float*)d_in[0];
    const float* v      = (const float*)d_in[1];
    const float* w_q    = (const float*)d_in[2];
    const float* b_q    = (const float*)d_in[3];
    const float* w_kc   = (const float*)d_in[4];
    const float* b_kc   = (const float*)d_in[5];
    const float* w_kd   = (const float*)d_in[6];
    const float* b_kd   = (const float*)d_in[7];
    const float* w_v    = (const float*)d_in[8];
    const float* b_v    = (const float*)d_in[9];
    const float* temp_c = (const float*)d_in[10];
    const float* temp_d = (const float*)d_in[11];
    const float* bn_g   = (const float*)d_in[12];
    const float* bn_b   = (const float*)d_in[13];
    const float* bn_m   = (const float*)d_in[14];
    const float* bn_v   = (const float*)d_in[15];
    float* out = (float*)d_out;

    float* ws   = (float*)d_ws;
    float* qv   = ws;                    // B*DO            = 16384
    float* wqkc = qv   + B*DO;           // B*NH*DO         = 131072
    float* wqkd = wqkc + B*NH*DO;        // 131072
    float* qbc  = wqkd + B*NH*DO;        // 512
    float* qbd  = qbc  + B*NH;           // 512
    float* lc   = qbd  + B*NH;           // B*NH*HW         = 524288
    float* gate = lc   + B*NH*HW;        // 524288
    float* p    = gate + B*NH*HW;        // 524288
    float* pv   = p    + B*NH*HW;        // 131072
    float* attn = pv   + B*NH*DO;        // 16384

    k1_qv      <<<B,            256, 0, stream>>>(q, w_q, b_q, qv);
    k2_wqk     <<<B*NH,         256, 0, stream>>>(qv, w_kc, b_kc, w_kd, b_kd, temp_c, temp_d,
                                                  wqkc, wqkd, qbc, qbd);
    k3_logits  <<<dim3(4, B),   256, 0, stream>>>(v, wqkc, wqkd, qbc, qbd, lc, gate);
    k4a_softmax<<<B*NH,         256, 0, stream>>>(lc, p);
    k4b_pool   <<<dim3(4, B),   256, 0, stream>>>(v, p, pv);
    k4c_attn   <<<B,            256, 0, stream>>>(pv, w_v, b_v, attn);
    k5_out     <<<dim3(DO, B),  256, 0, stream>>>(v, gate, attn, bn_g, bn_b, bn_m, bn_v, out);
}

// Round 2
// 117.473 us; speedup vs baseline: 1.2388x; 1.2388x over previous
//
#include <hip/hip_runtime.h>
#include <math.h>

#define B   64
#define DQ  512
#define DO  256
#define NH  8
#define DH  32
#define HW  1024

// ---------------------------------------------------------------- K1: qv = q @ w_q.T + b_q
__global__ void k1_qv(const float* __restrict__ q, const float* __restrict__ w_q,
                      const float* __restrict__ b_q, float* __restrict__ qv) {
    __shared__ float qs[DQ];
    int b = blockIdx.x, t = threadIdx.x;
    qs[t]       = q[b*DQ + t];
    qs[t + 256] = q[b*DQ + t + 256];
    __syncthreads();
    float acc = b_q[t];
    const float4* w4 = reinterpret_cast<const float4*>(w_q + t*DQ);
    #pragma unroll 4
    for (int k4 = 0; k4 < DQ/4; ++k4) {
        float4 w = w4[k4];
        acc += qs[k4*4+0]*w.x + qs[k4*4+1]*w.y + qs[k4*4+2]*w.z + qs[k4*4+3]*w.w;
    }
    qv[b*DO + t] = acc;
}

// ---------------------------------------------------------------- K2: fold qv into kc/kd weights
__global__ void k2_wqk(const float* __restrict__ qv,
                       const float* __restrict__ w_kc, const float* __restrict__ b_kc,
                       const float* __restrict__ w_kd, const float* __restrict__ b_kd,
                       const float* __restrict__ temp_c, const float* __restrict__ temp_d,
                       float* __restrict__ wqkc, float* __restrict__ wqkd,
                       float* __restrict__ qbc, float* __restrict__ qbd) {
    int bn = blockIdx.x;              // b*8 + n
    int n  = bn & 7;
    int t  = threadIdx.x;             // c
    __shared__ float qvs[DH];
    if (t < DH) qvs[t] = qv[(bn >> 3)*DO + n*DH + t];
    __syncthreads();
    float itc = 1.0f / temp_c[0];
    float itd = 1.0f / temp_d[0];
    float ac = 0.f, ad = 0.f;
    #pragma unroll
    for (int d = 0; d < DH; ++d) {
        float qd = qvs[d];
        ac += qd * w_kc[(n*DH + d)*DO + t];
        ad += qd * w_kd[(n*DH + d)*DO + t];
    }
    wqkc[bn*DO + t] = ac * itc;
    wqkd[bn*DO + t] = ad * itd;
    if (t == 0) {
        float sc = 0.f, sd = 0.f;
        for (int d = 0; d < DH; ++d) { sc += qvs[d]*b_kc[n*DH + d]; sd += qvs[d]*b_kd[n*DH + d]; }
        qbc[bn] = sc * itc;
        qbd[bn] = sd * itd;
    }
}

// ---------------------------------------------------------------- K3p: partial logits/gate pre-activations
// grid (4 s-chunks, 4 c-chunks, B); partials per (b, cc, n, s)
__global__ void k3p(const float* __restrict__ v,
                    const float* __restrict__ wqkc, const float* __restrict__ wqkd,
                    float* __restrict__ partc, float* __restrict__ partd) {
    int b  = blockIdx.z;
    int cc = blockIdx.y;
    int s  = blockIdx.x*256 + threadIdx.x;
    const float* vb = v    + (size_t)b*DO*HW + (size_t)cc*64*HW;
    const float* wc = wqkc + b*NH*DO + cc*64;
    const float* wd = wqkd + b*NH*DO + cc*64;
    float ac[NH] = {0.f,0.f,0.f,0.f,0.f,0.f,0.f,0.f};
    float ad[NH] = {0.f,0.f,0.f,0.f,0.f,0.f,0.f,0.f};
    for (int c0 = 0; c0 < 64; c0 += 4) {
        float v0 = vb[(c0+0)*HW + s];
        float v1 = vb[(c0+1)*HW + s];
        float v2 = vb[(c0+2)*HW + s];
        float v3 = vb[(c0+3)*HW + s];
        #pragma unroll
        for (int n = 0; n < NH; ++n) {
            ac[n] += v0*wc[n*DO + c0+0] + v1*wc[n*DO + c0+1]
                   + v2*wc[n*DO + c0+2] + v3*wc[n*DO + c0+3];
            ad[n] += v0*wd[n*DO + c0+0] + v1*wd[n*DO + c0+1]
                   + v2*wd[n*DO + c0+2] + v3*wd[n*DO + c0+3];
        }
    }
    size_t base = ((size_t)(b*4 + cc)*NH)*HW + s;
    #pragma unroll
    for (int n = 0; n < NH; ++n) {
        partc[base + n*HW] = ac[n];
        partd[base + n*HW] = ad[n];
    }
}

// ---------------------------------------------------------------- K4a: chunk-sum + softmax(p) + sigmoid gate
__global__ void k4a_softmax(const float* __restrict__ partc, const float* __restrict__ partd,
                            const float* __restrict__ qbc, const float* __restrict__ qbd,
                            float* __restrict__ p, float* __restrict__ gate) {
    int bn = blockIdx.x, t = threadIdx.x;
    int b = bn >> 3, n = bn & 7;
    float4 x = make_float4(0.f, 0.f, 0.f, 0.f);
    #pragma unroll
    for (int cc = 0; cc < 4; ++cc) {
        float4 pp = reinterpret_cast<const float4*>(partc + ((size_t)(b*4+cc)*NH + n)*HW)[t];
        x.x += pp.x; x.y += pp.y; x.z += pp.z; x.w += pp.w;
    }
    float qb = qbc[bn];
    x.x += qb; x.y += qb; x.z += qb; x.w += qb;

    __shared__ float red[256];
    float m = fmaxf(fmaxf(x.x, x.y), fmaxf(x.z, x.w));
    red[t] = m; __syncthreads();
    for (int o = 128; o > 0; o >>= 1) { if (t < o) red[t] = fmaxf(red[t], red[t+o]); __syncthreads(); }
    m = red[0]; __syncthreads();
    float e0 = __expf(x.x - m), e1 = __expf(x.y - m), e2 = __expf(x.z - m), e3 = __expf(x.w - m);
    red[t] = e0 + e1 + e2 + e3; __syncthreads();
    for (int o = 128; o > 0; o >>= 1) { if (t < o) red[t] += red[t+o]; __syncthreads(); }
    float inv = 1.0f / red[0];
    reinterpret_cast<float4*>(p + bn*HW)[t] = make_float4(e0*inv, e1*inv, e2*inv, e3*inv);

    float4 y = make_float4(0.f, 0.f, 0.f, 0.f);
    #pragma unroll
    for (int cc = 0; cc < 4; ++cc) {
        float4 pp = reinterpret_cast<const float4*>(partd + ((size_t)(b*4+cc)*NH + n)*HW)[t];
        y.x += pp.x; y.y += pp.y; y.z += pp.z; y.w += pp.w;
    }
    float qd = qbd[bn];
    float g0 = 1.0f/(1.0f + __expf(-(y.x + qd)));
    float g1 = 1.0f/(1.0f + __expf(-(y.y + qd)));
    float g2 = 1.0f/(1.0f + __expf(-(y.z + qd)));
    float g3 = 1.0f/(1.0f + __expf(-(y.w + qd)));
    reinterpret_cast<float4*>(gate + bn*HW)[t] = make_float4(g0, g1, g2, g3);
}

// ---------------------------------------------------------------- K4bp: partial pooled vector over s-chunks
// grid (4 c-chunks, 8 s-chunks, B); pvp[b][sq][n][c]
__global__ void k4bp(const float* __restrict__ v, const float* __restrict__ p,
                     float* __restrict__ pvp) {
    int b  = blockIdx.z;
    int sq = blockIdx.y;
    int cc = blockIdx.x;
    int t  = threadIdx.x;
    int cl = t & 63, sub = t >> 6;
    int c  = cc*64 + cl;
    int sbase = sq*128 + sub*32;
    const float4* v4 = reinterpret_cast<const float4*>(v + ((size_t)(b*DO + c))*HW + sbase);
    float acc[NH] = {0.f,0.f,0.f,0.f,0.f,0.f,0.f,0.f};
    #pragma unroll
    for (int i = 0; i < 8; ++i) {
        float4 vv = v4[i];
        #pragma unroll
        for (int n = 0; n < NH; ++n) {
            float4 pp = reinterpret_cast<const float4*>(p + (b*NH + n)*HW + sbase)[i];
            acc[n] += vv.x*pp.x + vv.y*pp.y + vv.z*pp.z + vv.w*pp.w;
        }
    }
    __shared__ float red[4][NH][64];
    #pragma unroll
    for (int n = 0; n < NH; ++n) red[sub][n][cl] = acc[n];
    __syncthreads();
    if (t < 64) {
        #pragma unroll
        for (int n = 0; n < NH; ++n) {
            float sum = red[0][n][t] + red[1][n][t] + red[2][n][t] + red[3][n][t];
            pvp[((size_t)(b*8 + sq)*NH + n)*DO + cc*64 + t] = sum;
        }
    }
}

// ---------------------------------------------------------------- K4c: sum s-chunks + attn = w_v·pv + b_v
__global__ void k4c_attn(const float* __restrict__ pvp, const float* __restrict__ w_v,
                         const float* __restrict__ b_v, float* __restrict__ attn) {
    int b = blockIdx.x, t = threadIdx.x;   // t = n*32 + d
    int n = t >> 5;
    __shared__ float pvs[NH*DO];
    for (int i = t; i < NH*DO; i += 256) {
        float sum = 0.f;
        #pragma unroll
        for (int sq = 0; sq < 8; ++sq) sum += pvp[(size_t)(b*8 + sq)*NH*DO + i];
        pvs[i] = sum;
    }
    __syncthreads();
    float acc = b_v[t];
    const float4* w4 = reinterpret_cast<const float4*>(w_v + t*DO);
    #pragma unroll 4
    for (int c4 = 0; c4 < DO/4; ++c4) {
        float4 w = w4[c4];
        int c = c4*4;
        acc += pvs[n*DO + c]*w.x + pvs[n*DO + c + 1]*w.y + pvs[n*DO + c + 2]*w.z + pvs[n*DO + c + 3]*w.w;
    }
    attn[b*NH*DH + t] = acc;
}

// ---------------------------------------------------------------- K5: out = leaky(bn(gate[s^T]*attn + v))
__global__ void k5_out(const float* __restrict__ v, const float* __restrict__ gate,
                       const float* __restrict__ attn,
                       const float* __restrict__ bn_g, const float* __restrict__ bn_b,
                       const float* __restrict__ bn_m, const float* __restrict__ bn_v,
                       float* __restrict__ out) {
    int c = blockIdx.x, b = blockIdx.y;
    int n = c >> 5, d = c & 31;
    int t = threadIdx.x;
    __shared__ float g[32*33];             // stride 33 kills transpose bank conflicts
    float4 gv = reinterpret_cast<const float4*>(gate + (b*NH + n)*HW)[t];
    int s0 = t*4;
    int ga = s0 >> 5, gb = s0 & 31;
    g[ga*33 + gb + 0] = gv.x;
    g[ga*33 + gb + 1] = gv.y;
    g[ga*33 + gb + 2] = gv.z;
    g[ga*33 + gb + 3] = gv.w;
    __syncthreads();
    float av   = attn[(b*NH + n)*DH + d];
    float inv  = bn_g[c] / sqrtf(bn_v[c] + 1e-5f);
    float mean = bn_m[c], beta = bn_b[c];
    size_t base = ((size_t)(b*DO + c))*HW;
    float4 r4 = reinterpret_cast<const float4*>(v + base)[t];
    int l = 4*t;
    int i_ = l >> 5, j_ = l & 31;          // gate index s = j*32 + i
    float x0 = g[(j_+0)*33 + i_]*av + r4.x;
    float x1 = g[(j_+1)*33 + i_]*av + r4.y;
    float x2 = g[(j_+2)*33 + i_]*av + r4.z;
    float x3 = g[(j_+3)*33 + i_]*av + r4.w;
    float y0 = (x0 - mean)*inv + beta; y0 = y0 >= 0.f ? y0 : 0.1f*y0;
    float y1 = (x1 - mean)*inv + beta; y1 = y1 >= 0.f ? y1 : 0.1f*y1;
    float y2 = (x2 - mean)*inv + beta; y2 = y2 >= 0.f ? y2 : 0.1f*y2;
    float y3 = (x3 - mean)*inv + beta; y3 = y3 >= 0.f ? y3 : 0.1f*y3;
    reinterpret_cast<float4*>(out + base)[t] = make_float4(y0, y1, y2, y3);
}

// ----------------------------------------------------------------
extern "C" void kernel_launch(void* const* d_in, const int* in_sizes, int n_in,
                              void* d_out, int out_size, void* d_ws, size_t ws_size,
                              hipStream_t stream) {
    const float* q      = (const float*)d_in[0];
    const float* v      = (const float*)d_in[1];
    const float* w_q    = (const float*)d_in[2];
    const float* b_q    = (const float*)d_in[3];
    const float* w_kc   = (const float*)d_in[4];
    const float* b_kc   = (const float*)d_in[5];
    const float* w_kd   = (const float*)d_in[6];
    const float* b_kd   = (const float*)d_in[7];
    const float* w_v    = (const float*)d_in[8];
    const float* b_v    = (const float*)d_in[9];
    const float* temp_c = (const float*)d_in[10];
    const float* temp_d = (const float*)d_in[11];
    const float* bn_g   = (const float*)d_in[12];
    const float* bn_b   = (const float*)d_in[13];
    const float* bn_m   = (const float*)d_in[14];
    const float* bn_v   = (const float*)d_in[15];
    float* out = (float*)d_out;

    float* ws    = (float*)d_ws;
    float* qv    = ws;                    // 16384
    float* wqkc  = qv    + B*DO;          // 131072
    float* wqkd  = wqkc  + B*NH*DO;       // 131072
    float* qbc   = wqkd  + B*NH*DO;       // 512
    float* qbd   = qbc   + B*NH;          // 512
    float* partc = qbd   + B*NH;          // B*4*NH*HW = 2097152
    float* partd = partc + B*4*NH*HW;     // 2097152
    float* p     = partd + B*4*NH*HW;     // 524288
    float* gate  = p     + B*NH*HW;       // 524288
    float* pvp   = gate  + B*NH*HW;       // B*8*NH*DO = 1048576
    float* attn  = pvp   + B*8*NH*DO;     // 16384

    k1_qv      <<<B,              256, 0, stream>>>(q, w_q, b_q, qv);
    k2_wqk     <<<B*NH,           256, 0, stream>>>(qv, w_kc, b_kc, w_kd, b_kd, temp_c, temp_d,
                                                    wqkc, wqkd, qbc, qbd);
    k3p        <<<dim3(4, 4, B),  256, 0, stream>>>(v, wqkc, wqkd, partc, partd);
    k4a_softmax<<<B*NH,           256, 0, stream>>>(partc, partd, qbc, qbd, p, gate);
    k4bp       <<<dim3(4, 8, B),  256, 0, stream>>>(v, p, pvp);
    k4c_attn   <<<B,              256, 0, stream>>>(pvp, w_v, b_v, attn);
    k5_out     <<<dim3(DO, B),    256, 0, stream>>>(v, gate, attn, bn_g, bn_b, bn_m, bn_v, out);
}